// Round 3
// baseline (283.629 us; speedup 1.0000x reference)
//
#include <hip/hip_runtime.h>
#include <math.h>

#define NNODES 50000
#define NEDGES 800000
#define INFEAT 256
#define OUTF   128
#define NEG_SLOPE 0.2f

// ---------------- zero ----------------
__global__ void kzero(int* p, int n) {
    int i = blockIdx.x * 256 + threadIdx.x;
    if (i < n) p[i] = 0;
}

// ---------------- degrees ----------------
__global__ void kdegrees(const int* __restrict__ src, const int* __restrict__ dst,
                         int* __restrict__ cnt_out, int* __restrict__ cnt_in, int E) {
    int i = blockIdx.x * 256 + threadIdx.x;
    if (i < E) {
        atomicAdd(&cnt_out[src[i]], 1);
        atomicAdd(&cnt_in[dst[i]], 1);
    }
}

// ---------------- exclusive scan (3 kernels) ----------------
__global__ void kscan_block(const int* __restrict__ cnt, int* __restrict__ out,
                            int* __restrict__ bsums, int n) {
    __shared__ int tmp[1024];
    int tid = threadIdx.x;
    int i = blockIdx.x * 1024 + tid;
    int v = (i < n) ? cnt[i] : 0;
    tmp[tid] = v;
    __syncthreads();
    for (int off = 1; off < 1024; off <<= 1) {
        int t = (tid >= off) ? tmp[tid - off] : 0;
        __syncthreads();
        tmp[tid] += t;
        __syncthreads();
    }
    if (i < n) out[i] = tmp[tid] - v;           // exclusive
    if (tid == 1023) bsums[blockIdx.x] = tmp[1023];
}

__global__ void kscan_tops(int* bsums, int nb, int* offs_last) {
    if (threadIdx.x == 0 && blockIdx.x == 0) {
        int run = 0;
        for (int b = 0; b < nb; b++) { int t = bsums[b]; bsums[b] = run; run += t; }
        offs_last[0] = run;                      // offsets[NNODES] = E
    }
}

__global__ void kscan_add(int* __restrict__ out, const int* __restrict__ bsums, int n) {
    int i = blockIdx.x * 1024 + threadIdx.x;
    if (i < n) out[i] += bsums[blockIdx.x];
}

// ---------------- bucket edges by dst ----------------
__global__ void kbucket(const int* __restrict__ dst, const int* __restrict__ offs,
                        int* __restrict__ fill, int* __restrict__ ebd, int E) {
    int i = blockIdx.x * 256 + threadIdx.x;
    if (i < E) {
        int d = dst[i];
        int p = atomicAdd(&fill[d], 1);
        ebd[offs[d] + p] = i;
    }
}

// ---------------- GEMM: h = rsqrt(max(out_deg,1)) * (feat @ W) ----------------
// M=50000, K=256, N=128. block 256 threads, tile BM=64 x BN=128, BK=32.
#define BM 64
#define BK 32
__launch_bounds__(256)
__global__ void kgemm(const float* __restrict__ feat, const float* __restrict__ W,
                      const int* __restrict__ cnt_out, float* __restrict__ h, int M) {
    __shared__ float As[BK][68];    // [k][row], stride 68 -> conflict-free b128 reads
    __shared__ float Bs[BK][128];
    int tid = threadIdx.x;
    int tr = tid >> 4;
    int tc = tid & 15;
    int m0 = blockIdx.x * BM;
    float acc[4][8] = {};

    for (int kt = 0; kt < INFEAT; kt += BK) {
        // stage A: 64 rows x 32 k = 512 float4; 2 per thread
        #pragma unroll
        for (int r = 0; r < 2; r++) {
            int fi = tid * 2 + r;
            int row = fi >> 3;          // 0..63
            int kq  = fi & 7;           // 0..7
            int gr = m0 + row;
            float4 v = make_float4(0.f, 0.f, 0.f, 0.f);
            if (gr < M) v = *(const float4*)&feat[(size_t)gr * INFEAT + kt + kq * 4];
            As[kq * 4 + 0][row] = v.x;
            As[kq * 4 + 1][row] = v.y;
            As[kq * 4 + 2][row] = v.z;
            As[kq * 4 + 3][row] = v.w;
        }
        // stage B: 32 rows x 128 cols = 1024 float4; 4 per thread
        #pragma unroll
        for (int r = 0; r < 4; r++) {
            int fi = tid + 256 * r;
            int row = fi >> 5;          // 0..31
            int c4  = fi & 31;          // 0..31
            float4 v = *(const float4*)&W[(size_t)(kt + row) * OUTF + c4 * 4];
            *(float4*)&Bs[row][c4 * 4] = v;
        }
        __syncthreads();
        #pragma unroll
        for (int kk = 0; kk < BK; kk++) {
            float4 a  = *(const float4*)&As[kk][tr * 4];
            float4 b0 = *(const float4*)&Bs[kk][tc * 4];
            float4 b1 = *(const float4*)&Bs[kk][64 + tc * 4];
            float av[4] = {a.x, a.y, a.z, a.w};
            float bv[8] = {b0.x, b0.y, b0.z, b0.w, b1.x, b1.y, b1.z, b1.w};
            #pragma unroll
            for (int i = 0; i < 4; i++)
                #pragma unroll
                for (int j = 0; j < 8; j++)
                    acc[i][j] += av[i] * bv[j];
        }
        __syncthreads();
    }
    #pragma unroll
    for (int i = 0; i < 4; i++) {
        int gr = m0 + tr * 4 + i;
        if (gr < M) {
            int c = cnt_out[gr];
            float sc = rsqrtf((float)(c < 1 ? 1 : c));
            float4 o0 = make_float4(acc[i][0] * sc, acc[i][1] * sc, acc[i][2] * sc, acc[i][3] * sc);
            float4 o1 = make_float4(acc[i][4] * sc, acc[i][5] * sc, acc[i][6] * sc, acc[i][7] * sc);
            *(float4*)&h[(size_t)gr * OUTF + tc * 4] = o0;
            *(float4*)&h[(size_t)gr * OUTF + 64 + tc * 4] = o1;
        }
    }
}

// ---------------- per-dst aggregation: softmax + scatter-sum ----------------
// one wave (64 lanes) per destination node; lane owns 2 feature cols (float2).
// Edge ids + src ids of a bucket are loaded one-per-lane (parallel), then
// broadcast via __shfl -> no serial dependent-load chain.
__launch_bounds__(256)
__global__ void kaggregate(const float* __restrict__ h, const int* __restrict__ src,
                           const int* __restrict__ ebd, const int* __restrict__ offs,
                           const int* __restrict__ cnt_in, const float* __restrict__ bias,
                           float* __restrict__ e_tmp, float* __restrict__ out_rst,
                           float* __restrict__ out_es, int nnodes) {
    int wid = threadIdx.x >> 6;
    int lane = threadIdx.x & 63;
    int n = blockIdx.x * 4 + wid;
    if (n >= nnodes) return;

    int off = offs[n];
    int deg = cnt_in[n];
    int c = lane * 2;

    float2 hd = *(const float2*)&h[(size_t)n * OUTF + c];
    float tx = tanhf(hd.x), ty = tanhf(hd.y);

    float2 acc = make_float2(0.f, 0.f);
    float runmax = -INFINITY;

    if (deg <= 64) {
        int eid = 0, s = 0;
        if (lane < deg) { eid = ebd[off + lane]; s = src[eid]; }
        float myv = -INFINITY;
        for (int j = 0; j < deg; j++) {
            int sj = __shfl(s, j, 64);
            float2 hs = *(const float2*)&h[(size_t)sj * OUTF + c];
            acc.x += hs.x; acc.y += hs.y;
            float p = hs.x * tx + hs.y * ty;
            #pragma unroll
            for (int m = 1; m < 64; m <<= 1) p += __shfl_xor(p, m, 64);
            float e = p > 0.f ? p : NEG_SLOPE * p;
            runmax = fmaxf(runmax, e);
            if (j == lane) myv = e;
        }
        if (deg > 0) {
            float v = (lane < deg) ? expf(myv - runmax) : 0.f;
            float sum = v;
            #pragma unroll
            for (int m = 1; m < 64; m <<= 1) sum += __shfl_xor(sum, m, 64);
            float inv = 1.f / sum;
            if (lane < deg) out_es[eid] = v * inv;
        }
    } else {
        // rare fallback (deg > 64): chunked, e values spilled to e_tmp
        for (int base = 0; base < deg; base += 64) {
            int cnt = min(64, deg - base);
            int s = 0;
            if (lane < cnt) s = src[ebd[off + base + lane]];
            for (int j = 0; j < cnt; j++) {
                int sj = __shfl(s, j, 64);
                float2 hs = *(const float2*)&h[(size_t)sj * OUTF + c];
                acc.x += hs.x; acc.y += hs.y;
                float p = hs.x * tx + hs.y * ty;
                #pragma unroll
                for (int m = 1; m < 64; m <<= 1) p += __shfl_xor(p, m, 64);
                float e = p > 0.f ? p : NEG_SLOPE * p;
                runmax = fmaxf(runmax, e);
                if (lane == 0) e_tmp[off + base + j] = e;
            }
        }
        __threadfence();
        float lsum = 0.f;
        for (int j = lane; j < deg; j += 64) {
            float v = expf(e_tmp[off + j] - runmax);
            e_tmp[off + j] = v;
            lsum += v;
        }
        #pragma unroll
        for (int m = 1; m < 64; m <<= 1) lsum += __shfl_xor(lsum, m, 64);
        float inv = 1.f / lsum;
        __threadfence();
        for (int j = lane; j < deg; j += 64)
            out_es[ebd[off + j]] = e_tmp[off + j] * inv;
    }

    float sc = rsqrtf((float)(deg < 1 ? 1 : deg));
    float2 b2 = *(const float2*)&bias[c];
    float2 r = make_float2(acc.x * sc + b2.x, acc.y * sc + b2.y);
    *(float2*)&out_rst[(size_t)n * OUTF + c] = r;
}

// ---------------- launch ----------------
extern "C" void kernel_launch(void* const* d_in, const int* in_sizes, int n_in,
                              void* d_out, int out_size, void* d_ws, size_t ws_size,
                              hipStream_t stream) {
    const float* feat = (const float*)d_in[0];
    const float* W    = (const float*)d_in[1];
    const float* bias = (const float*)d_in[2];
    const int*   src  = (const int*)d_in[3];
    const int*   dst  = (const int*)d_in[4];

    float* out_rst = (float*)d_out;
    float* out_es  = (float*)d_out + (size_t)NNODES * OUTF;

    char* ws = (char*)d_ws;
    size_t o = 0;
    auto alloc = [&](size_t bytes) { void* p = ws + o; o += (bytes + 255) & ~(size_t)255; return p; };
    int*   cnt_out = (int*)alloc(NNODES * 4);
    int*   cnt_in  = (int*)alloc(NNODES * 4);
    int*   fill    = (int*)alloc(NNODES * 4);
    int*   offs    = (int*)alloc((NNODES + 1) * 4);
    int*   bsums   = (int*)alloc(64 * 4);
    int*   ebd     = (int*)alloc(NEDGES * 4);
    float* e_tmp   = (float*)alloc(NEDGES * 4);
    float* h       = (float*)alloc((size_t)NNODES * OUTF * 4);
    (void)o; (void)ws_size; (void)in_sizes; (void)n_in; (void)out_size;

    // zero cnt_out, cnt_in, fill (contiguous padded regions at base of ws)
    const int zints = (int)(3 * (((size_t)NNODES * 4 + 255) & ~(size_t)255) / 4);
    kzero<<<(zints + 255) / 256, 256, 0, stream>>>((int*)d_ws, zints);

    kdegrees<<<(NEDGES + 255) / 256, 256, 0, stream>>>(src, dst, cnt_out, cnt_in, NEDGES);

    const int nb = (NNODES + 1023) / 1024;   // 49
    kscan_block<<<nb, 1024, 0, stream>>>(cnt_in, offs, bsums, NNODES);
    kscan_tops<<<1, 64, 0, stream>>>(bsums, nb, offs + NNODES);
    kscan_add<<<nb, 1024, 0, stream>>>(offs, bsums, NNODES);

    kbucket<<<(NEDGES + 255) / 256, 256, 0, stream>>>(dst, offs, fill, ebd, NEDGES);

    kgemm<<<(NNODES + BM - 1) / BM, 256, 0, stream>>>(feat, W, cnt_out, h, NNODES);

    kaggregate<<<(NNODES + 3) / 4, 256, 0, stream>>>(h, src, ebd, offs, cnt_in, bias,
                                                     e_tmp, out_rst, out_es, NNODES);
}

// Round 5
// 253.481 us; speedup vs baseline: 1.1189x; 1.1189x over previous
//
#include <hip/hip_runtime.h>
#include <math.h>

#define NNODES 50000
#define NEDGES 800000
#define INFEAT 256
#define OUTF   128
#define NEG_SLOPE 0.2f

// ---------------- zero ----------------
__global__ void kzero(int* p, int n) {
    int i = blockIdx.x * 256 + threadIdx.x;
    if (i < n) p[i] = 0;
}

// ---------------- degrees ----------------
__global__ void kdegrees(const int* __restrict__ src, const int* __restrict__ dst,
                         int* __restrict__ cnt_out, int* __restrict__ cnt_in, int E) {
    int i = blockIdx.x * 256 + threadIdx.x;
    if (i < E) {
        atomicAdd(&cnt_out[src[i]], 1);
        atomicAdd(&cnt_in[dst[i]], 1);
    }
}

// ---------------- scan, 2 kernels ----------------
__global__ void kblocksum(const int* __restrict__ cnt, int* __restrict__ bsums, int n) {
    __shared__ int red[16];
    int tid = threadIdx.x;
    int i = blockIdx.x * 1024 + tid;
    int v = (i < n) ? cnt[i] : 0;
    #pragma unroll
    for (int m = 1; m < 64; m <<= 1) v += __shfl_xor(v, m, 64);
    if ((tid & 63) == 0) red[tid >> 6] = v;
    __syncthreads();
    if (tid < 16) {
        int t = red[tid];
        #pragma unroll
        for (int m = 1; m < 16; m <<= 1) t += __shfl_xor(t, m, 64);
        if (tid == 0) bsums[blockIdx.x] = t;
    }
}

__global__ void kscanfull(const int* __restrict__ cnt, const int* __restrict__ bsums,
                          int* __restrict__ out, int n, int nb) {
    __shared__ int tmp[1024];
    __shared__ int base_s;
    int tid = threadIdx.x;
    int b = blockIdx.x;
    int i = b * 1024 + tid;
    if (tid == 0) {
        int run = 0;
        for (int bb = 0; bb < b; bb++) run += bsums[bb];
        base_s = run;
        if (b == nb - 1) out[n] = run + bsums[b];
    }
    int v = (i < n) ? cnt[i] : 0;
    tmp[tid] = v;
    __syncthreads();
    for (int off = 1; off < 1024; off <<= 1) {
        int t = (tid >= off) ? tmp[tid - off] : 0;
        __syncthreads();
        tmp[tid] += t;
        __syncthreads();
    }
    if (i < n) out[i] = tmp[tid] - v + base_s;
}

// ---------------- bucket edges by dst ----------------
__global__ void kbucket(const int* __restrict__ dst, const int* __restrict__ offs,
                        int* __restrict__ fill, int* __restrict__ ebd, int E) {
    int i = blockIdx.x * 256 + threadIdx.x;
    if (i < E) {
        int d = dst[i];
        int p = atomicAdd(&fill[d], 1);
        ebd[offs[d] + p] = i;
    }
}

// ---------------- GEMM: h = rsqrt(max(out_deg,1)) * (feat @ W) ----------------
#define BM 64
#define BK 32
__launch_bounds__(256)
__global__ void kgemm(const float* __restrict__ feat, const float* __restrict__ W,
                      const int* __restrict__ cnt_out, float* __restrict__ h, int M) {
    __shared__ float As[BK][68];
    __shared__ float Bs[BK][128];
    int tid = threadIdx.x;
    int tr = tid >> 4;
    int tc = tid & 15;
    int m0 = blockIdx.x * BM;
    float acc[4][8] = {};

    for (int kt = 0; kt < INFEAT; kt += BK) {
        #pragma unroll
        for (int r = 0; r < 2; r++) {
            int fi = tid * 2 + r;
            int row = fi >> 3;
            int kq  = fi & 7;
            int gr = m0 + row;
            float4 v = make_float4(0.f, 0.f, 0.f, 0.f);
            if (gr < M) v = *(const float4*)&feat[(size_t)gr * INFEAT + kt + kq * 4];
            As[kq * 4 + 0][row] = v.x;
            As[kq * 4 + 1][row] = v.y;
            As[kq * 4 + 2][row] = v.z;
            As[kq * 4 + 3][row] = v.w;
        }
        #pragma unroll
        for (int r = 0; r < 4; r++) {
            int fi = tid + 256 * r;
            int row = fi >> 5;
            int c4  = fi & 31;
            float4 v = *(const float4*)&W[(size_t)(kt + row) * OUTF + c4 * 4];
            *(float4*)&Bs[row][c4 * 4] = v;
        }
        __syncthreads();
        #pragma unroll
        for (int kk = 0; kk < BK; kk++) {
            float4 a  = *(const float4*)&As[kk][tr * 4];
            float4 b0 = *(const float4*)&Bs[kk][tc * 4];
            float4 b1 = *(const float4*)&Bs[kk][64 + tc * 4];
            float av[4] = {a.x, a.y, a.z, a.w};
            float bv[8] = {b0.x, b0.y, b0.z, b0.w, b1.x, b1.y, b1.z, b1.w};
            #pragma unroll
            for (int i = 0; i < 4; i++)
                #pragma unroll
                for (int j = 0; j < 8; j++)
                    acc[i][j] += av[i] * bv[j];
        }
        __syncthreads();
    }
    #pragma unroll
    for (int i = 0; i < 4; i++) {
        int gr = m0 + tr * 4 + i;
        if (gr < M) {
            int c = cnt_out[gr];
            float sc = rsqrtf((float)(c < 1 ? 1 : c));
            float4 o0 = make_float4(acc[i][0] * sc, acc[i][1] * sc, acc[i][2] * sc, acc[i][3] * sc);
            float4 o1 = make_float4(acc[i][4] * sc, acc[i][5] * sc, acc[i][6] * sc, acc[i][7] * sc);
            *(float4*)&h[(size_t)gr * OUTF + tc * 4] = o0;
            *(float4*)&h[(size_t)gr * OUTF + 64 + tc * 4] = o1;
        }
    }
}

// ---------------- per-dst aggregation: softmax + scatter-sum ----------------
// one wave per dst node. 4 groups of 16 lanes process 4 edges concurrently;
// lane (g,t) owns feature cols t*8..t*8+7. Dot reduce = 4 shfl steps in-group.
// NOTE: all __shfl ops run with the FULL wave active (divergent-branch
// bpermute from an inactive source lane returns undefined — round-4 bug).
__launch_bounds__(256)
__global__ void kaggregate(const float* __restrict__ h, const int* __restrict__ src,
                           const int* __restrict__ ebd, const int* __restrict__ offs,
                           const int* __restrict__ cnt_in, const float* __restrict__ bias,
                           float* __restrict__ e_tmp, float* __restrict__ out_rst,
                           float* __restrict__ out_es, int nnodes) {
    int wid = threadIdx.x >> 6;
    int lane = threadIdx.x & 63;
    int n = blockIdx.x * 4 + wid;
    if (n >= nnodes) return;

    int off = offs[n];
    int deg = cnt_in[n];

    if (deg <= 64) {
        int g = lane >> 4;          // group 0..3
        int t = lane & 15;          // sublane
        int c = t * 8;              // 8 cols per lane

        float4 th0 = *(const float4*)&h[(size_t)n * OUTF + c];
        float4 th1 = *(const float4*)&h[(size_t)n * OUTF + c + 4];
        th0.x = tanhf(th0.x); th0.y = tanhf(th0.y); th0.z = tanhf(th0.z); th0.w = tanhf(th0.w);
        th1.x = tanhf(th1.x); th1.y = tanhf(th1.y); th1.z = tanhf(th1.z); th1.w = tanhf(th1.w);

        int eid = 0, s = 0;
        if (lane < deg) { eid = ebd[off + lane]; s = src[eid]; }

        float4 acc0 = make_float4(0.f, 0.f, 0.f, 0.f);
        float4 acc1 = make_float4(0.f, 0.f, 0.f, 0.f);
        float myv = -INFINITY;      // e value of edge m = 4*t + g

        for (int base = 0; base < deg; base += 4) {
            int m = base + g;
            int sj = __shfl(s, m, 64);          // full wave active
            float4 hs0 = make_float4(0.f, 0.f, 0.f, 0.f);
            float4 hs1 = make_float4(0.f, 0.f, 0.f, 0.f);
            if (m < deg) {
                hs0 = *(const float4*)&h[(size_t)sj * OUTF + c];
                hs1 = *(const float4*)&h[(size_t)sj * OUTF + c + 4];
            }
            acc0.x += hs0.x; acc0.y += hs0.y; acc0.z += hs0.z; acc0.w += hs0.w;
            acc1.x += hs1.x; acc1.y += hs1.y; acc1.z += hs1.z; acc1.w += hs1.w;
            float p = hs0.x * th0.x + hs0.y * th0.y + hs0.z * th0.z + hs0.w * th0.w
                    + hs1.x * th1.x + hs1.y * th1.y + hs1.z * th1.z + hs1.w * th1.w;
            #pragma unroll
            for (int msk = 1; msk < 16; msk <<= 1) p += __shfl_xor(p, msk, 64);
            float e = p > 0.f ? p : NEG_SLOPE * p;
            if (m < deg && t == (base >> 2)) myv = e;
        }

        if (deg > 0) {
            float mx = myv;
            #pragma unroll
            for (int msk = 1; msk < 64; msk <<= 1) mx = fmaxf(mx, __shfl_xor(mx, msk, 64));
            int m = 4 * t + g;      // the edge this lane holds
            float v = (m < deg) ? expf(myv - mx) : 0.f;
            float sum = v;
            #pragma unroll
            for (int msk = 1; msk < 64; msk <<= 1) sum += __shfl_xor(sum, msk, 64);
            float inv = 1.f / sum;
            int eidm = __shfl(eid, m, 64);      // FULL WAVE ACTIVE (fix)
            if (m < deg) out_es[eidm] = v * inv;
        }

        #pragma unroll
        for (int msk = 16; msk < 64; msk <<= 1) {
            acc0.x += __shfl_xor(acc0.x, msk, 64);
            acc0.y += __shfl_xor(acc0.y, msk, 64);
            acc0.z += __shfl_xor(acc0.z, msk, 64);
            acc0.w += __shfl_xor(acc0.w, msk, 64);
            acc1.x += __shfl_xor(acc1.x, msk, 64);
            acc1.y += __shfl_xor(acc1.y, msk, 64);
            acc1.z += __shfl_xor(acc1.z, msk, 64);
            acc1.w += __shfl_xor(acc1.w, msk, 64);
        }
        if (g == 0) {
            float sc = rsqrtf((float)(deg < 1 ? 1 : deg));
            float4 b0 = *(const float4*)&bias[c];
            float4 b1 = *(const float4*)&bias[c + 4];
            float4 r0 = make_float4(acc0.x * sc + b0.x, acc0.y * sc + b0.y,
                                    acc0.z * sc + b0.z, acc0.w * sc + b0.w);
            float4 r1 = make_float4(acc1.x * sc + b1.x, acc1.y * sc + b1.y,
                                    acc1.z * sc + b1.z, acc1.w * sc + b1.w);
            *(float4*)&out_rst[(size_t)n * OUTF + c] = r0;
            *(float4*)&out_rst[(size_t)n * OUTF + c + 4] = r1;
        }
    } else {
        // rare fallback (deg > 64): full-wave per edge, e spilled to e_tmp
        int c = lane * 2;
        float2 hd = *(const float2*)&h[(size_t)n * OUTF + c];
        float tx = tanhf(hd.x), ty = tanhf(hd.y);
        float2 acc = make_float2(0.f, 0.f);
        float runmax = -INFINITY;
        for (int base = 0; base < deg; base += 64) {
            int cnt = min(64, deg - base);
            int s = 0;
            if (lane < cnt) s = src[ebd[off + base + lane]];
            for (int j = 0; j < cnt; j++) {
                int sj = __shfl(s, j, 64);
                float2 hs = *(const float2*)&h[(size_t)sj * OUTF + c];
                acc.x += hs.x; acc.y += hs.y;
                float p = hs.x * tx + hs.y * ty;
                #pragma unroll
                for (int m = 1; m < 64; m <<= 1) p += __shfl_xor(p, m, 64);
                float e = p > 0.f ? p : NEG_SLOPE * p;
                runmax = fmaxf(runmax, e);
                if (lane == 0) e_tmp[off + base + j] = e;
            }
        }
        __threadfence();
        float lsum = 0.f;
        for (int j = lane; j < deg; j += 64) {
            float v = expf(e_tmp[off + j] - runmax);
            e_tmp[off + j] = v;
            lsum += v;
        }
        #pragma unroll
        for (int m = 1; m < 64; m <<= 1) lsum += __shfl_xor(lsum, m, 64);
        float inv = 1.f / lsum;
        __threadfence();
        for (int j = lane; j < deg; j += 64)
            out_es[ebd[off + j]] = e_tmp[off + j] * inv;

        float sc = rsqrtf((float)deg);
        float2 b2 = *(const float2*)&bias[c];
        float2 r = make_float2(acc.x * sc + b2.x, acc.y * sc + b2.y);
        *(float2*)&out_rst[(size_t)n * OUTF + c] = r;
    }
}

// ---------------- launch ----------------
extern "C" void kernel_launch(void* const* d_in, const int* in_sizes, int n_in,
                              void* d_out, int out_size, void* d_ws, size_t ws_size,
                              hipStream_t stream) {
    const float* feat = (const float*)d_in[0];
    const float* W    = (const float*)d_in[1];
    const float* bias = (const float*)d_in[2];
    const int*   src  = (const int*)d_in[3];
    const int*   dst  = (const int*)d_in[4];

    float* out_rst = (float*)d_out;
    float* out_es  = (float*)d_out + (size_t)NNODES * OUTF;

    char* ws = (char*)d_ws;
    size_t o = 0;
    auto alloc = [&](size_t bytes) { void* p = ws + o; o += (bytes + 255) & ~(size_t)255; return p; };
    int*   cnt_out = (int*)alloc(NNODES * 4);
    int*   cnt_in  = (int*)alloc(NNODES * 4);
    int*   fill    = (int*)alloc(NNODES * 4);
    int*   offs    = (int*)alloc((NNODES + 1) * 4);
    int*   bsums   = (int*)alloc(64 * 4);
    int*   ebd     = (int*)alloc(NEDGES * 4);
    float* e_tmp   = (float*)alloc(NEDGES * 4);
    float* h       = (float*)alloc((size_t)NNODES * OUTF * 4);
    (void)o; (void)ws_size; (void)in_sizes; (void)n_in; (void)out_size;

    const int zints = (int)(3 * (((size_t)NNODES * 4 + 255) & ~(size_t)255) / 4);
    kzero<<<(zints + 255) / 256, 256, 0, stream>>>((int*)d_ws, zints);

    kdegrees<<<(NEDGES + 255) / 256, 256, 0, stream>>>(src, dst, cnt_out, cnt_in, NEDGES);

    const int nb = (NNODES + 1023) / 1024;   // 49
    kblocksum<<<nb, 1024, 0, stream>>>(cnt_in, bsums, NNODES);
    kscanfull<<<nb, 1024, 0, stream>>>(cnt_in, bsums, offs, NNODES, nb);

    kbucket<<<(NEDGES + 255) / 256, 256, 0, stream>>>(dst, offs, fill, ebd, NEDGES);

    kgemm<<<(NNODES + BM - 1) / BM, 256, 0, stream>>>(feat, W, cnt_out, h, NNODES);

    kaggregate<<<(NNODES + 3) / 4, 256, 0, stream>>>(h, src, ebd, offs, cnt_in, bias,
                                                     e_tmp, out_rst, out_es, NNODES);
}